// Round 10
// baseline (117.938 us; speedup 1.0000x reference)
//
#include <hip/hip_runtime.h>

#define H 1024
#define W 1024
#define NIMG 8
#define CPT 4                  // columns per thread
#define TH 8                   // output rows per wave-tile
#define NBX 4                  // 64 lanes * 4 cols * 4 = 1024 cols
#define NBYT (H / TH)          // 128
#define NWAVES (NBX * NBYT * NIMG)   // 4096 single-wave blocks = 16/CU
#define EPS 1e-5f

struct RS { float I[CPT], J[CPT], II[CPT], JJ[CPT], IJ[CPT]; };

__device__ __forceinline__ float4 ld4(const float* p) {
  return *reinterpret_cast<const float4*>(p);
}

// Horizontal 9-box rowsums for 4 output columns from 12 raw px.
__device__ __forceinline__ void rowsum(const float4& iL, const float4& iC,
                                       const float4& iR, const float4& jL,
                                       const float4& jC, const float4& jR,
                                       RS& o) {
  const float a[12] = {iL.x,iL.y,iL.z,iL.w, iC.x,iC.y,iC.z,iC.w,
                       iR.x,iR.y,iR.z,iR.w};
  const float b[12] = {jL.x,jL.y,jL.z,jL.w, jC.x,jC.y,jC.z,jC.w,
                       jR.x,jR.y,jR.z,jR.w};
  float sI=0.f, sJ=0.f, sII=0.f, sJJ=0.f, sIJ=0.f;
  #pragma unroll
  for (int k = 0; k < 9; ++k) {
    sI += a[k]; sJ += b[k];
    sII = fmaf(a[k], a[k], sII);
    sJJ = fmaf(b[k], b[k], sJJ);
    sIJ = fmaf(a[k], b[k], sIJ);
  }
  o.I[0]=sI; o.J[0]=sJ; o.II[0]=sII; o.JJ[0]=sJJ; o.IJ[0]=sIJ;
  #pragma unroll
  for (int i = 1; i < CPT; ++i) {
    float an=a[i+8], al=a[i-1], bn=b[i+8], bl=b[i-1];
    sI += an - al;  sJ += bn - bl;
    sII = fmaf(-al, al, fmaf(an, an, sII));
    sJJ = fmaf(-bl, bl, fmaf(bn, bn, sJJ));
    sIJ = fmaf(-al, bl, fmaf(an, bn, sIJ));
    o.I[i]=sI; o.J[i]=sJ; o.II[i]=sII; o.JJ[i]=sJJ; o.IJ[i]=sIJ;
  }
}

// 1-wave blocks, no LDS, no barriers. KEY FIX vs R9: all 12 float4 loads of
// an iteration are issued RAW (no edge-select uses between load groups), so
// the compiler's waitcnt lands once per iteration after the full batch.
__global__ __launch_bounds__(64, 4)
void ncc_main(const float* __restrict__ I, const float* __restrict__ J,
              float* __restrict__ partial) {
  const int lane = threadIdx.x;           // 0..63
  const int gx = blockIdx.x;
  const int n  = blockIdx.y;              // image (XCD-constant per (gx,n))
  const int gy = blockIdx.z;
  const int X  = gx * 256 + lane * CPT;
  const int y0 = gy * TH;
  const bool okL = (X >= 4);
  const bool okR = (X + 8 <= W);
  const int xl = okL ? X - 4 : X;         // clamped (loop-invariant)
  const int xr = okR ? X + 4 : X;
  const size_t img_off = (size_t)n * H * W;
  const float* Ip = I + img_off;
  const float* Jp = J + img_off;

  float wI[CPT], wJ[CPT], wII[CPT], wJJ[CPT], wIJ[CPT];
  #pragma unroll
  for (int i = 0; i < CPT; ++i) { wI[i]=wJ[i]=wII[i]=wJJ[i]=wIJ[i]=0.f; }
  float acc = 0.f;
  const float inv81 = 1.0f / 81.0f;

  // ---- warm-up: rows y0-4 .. y0+4 (9 rows) -> window for output y0 ----
  #pragma unroll 1
  for (int k = 0; k < 9; ++k) {
    const int r = y0 - 4 + k;
    if ((unsigned)r < (unsigned)H) {      // wave-uniform
      const float* Ir = Ip + (size_t)r * W;
      const float* Jr = Jp + (size_t)r * W;
      float4 iL = ld4(Ir + xl), iC = ld4(Ir + X), iR = ld4(Ir + xr);
      float4 jL = ld4(Jr + xl), jC = ld4(Jr + X), jR = ld4(Jr + xr);
      if (!okL) { iL = make_float4(0,0,0,0); jL = make_float4(0,0,0,0); }
      if (!okR) { iR = make_float4(0,0,0,0); jR = make_float4(0,0,0,0); }
      RS o; rowsum(iL,iC,iR,jL,jC,jR,o);
      #pragma unroll
      for (int i = 0; i < CPT; ++i) {
        wI[i] += o.I[i];  wJ[i] += o.J[i];
        wII[i] += o.II[i]; wJJ[i] += o.JJ[i]; wIJ[i] += o.IJ[i];
      }
    }
  }
  #pragma unroll
  for (int i = 0; i < CPT; ++i) {
    float cross = fmaf(-(wI[i] * wJ[i]), inv81, wIJ[i]);
    float Iv    = fmaf(-(wI[i] * wI[i]), inv81, wII[i]);
    float Jv    = fmaf(-(wJ[i] * wJ[i]), inv81, wJJ[i]);
    acc = fmaf(cross * cross,
               __builtin_amdgcn_rcpf(fmaf(Iv, Jv, EPS)), acc);
  }

  // ---- steady: enter y0+5+k, leave y0-4+k, emit y0+1+k ----
  #pragma unroll 1
  for (int k = 0; k < TH - 1; ++k) {
    const int re = y0 + 5 + k;
    const int rl = y0 - 4 + k;
    const bool ev = (unsigned)re < (unsigned)H;   // wave-uniform
    const bool lv = (unsigned)rl < (unsigned)H;   // wave-uniform
    if (ev & lv) {
      const float* IrE = Ip + (size_t)re * W;
      const float* JrE = Jp + (size_t)re * W;
      const float* IrL = Ip + (size_t)rl * W;
      const float* JrL = Jp + (size_t)rl * W;
      // ALL 12 loads issued raw, back-to-back -> single wait point
      float4 eiL = ld4(IrE + xl), eiC = ld4(IrE + X), eiR = ld4(IrE + xr);
      float4 ejL = ld4(JrE + xl), ejC = ld4(JrE + X), ejR = ld4(JrE + xr);
      float4 liL = ld4(IrL + xl), liC = ld4(IrL + X), liR = ld4(IrL + xr);
      float4 ljL = ld4(JrL + xl), ljC = ld4(JrL + X), ljR = ld4(JrL + xr);
      if (!okL) {
        eiL = make_float4(0,0,0,0); ejL = make_float4(0,0,0,0);
        liL = make_float4(0,0,0,0); ljL = make_float4(0,0,0,0);
      }
      if (!okR) {
        eiR = make_float4(0,0,0,0); ejR = make_float4(0,0,0,0);
        liR = make_float4(0,0,0,0); ljR = make_float4(0,0,0,0);
      }
      RS oe, ol;
      rowsum(eiL,eiC,eiR,ejL,ejC,ejR,oe);
      rowsum(liL,liC,liR,ljL,ljC,ljR,ol);
      #pragma unroll
      for (int i = 0; i < CPT; ++i) {
        wI[i]  += oe.I[i]  - ol.I[i];
        wJ[i]  += oe.J[i]  - ol.J[i];
        wII[i] += oe.II[i] - ol.II[i];
        wJJ[i] += oe.JJ[i] - ol.JJ[i];
        wIJ[i] += oe.IJ[i] - ol.IJ[i];
      }
    } else {
      // rare y-edge path (first/last tile of each image)
      if (ev) {
        const float* Ir = Ip + (size_t)re * W;
        const float* Jr = Jp + (size_t)re * W;
        float4 iL = ld4(Ir + xl), iC = ld4(Ir + X), iR = ld4(Ir + xr);
        float4 jL = ld4(Jr + xl), jC = ld4(Jr + X), jR = ld4(Jr + xr);
        if (!okL) { iL = make_float4(0,0,0,0); jL = make_float4(0,0,0,0); }
        if (!okR) { iR = make_float4(0,0,0,0); jR = make_float4(0,0,0,0); }
        RS o; rowsum(iL,iC,iR,jL,jC,jR,o);
        #pragma unroll
        for (int i = 0; i < CPT; ++i) {
          wI[i] += o.I[i];  wJ[i] += o.J[i];
          wII[i] += o.II[i]; wJJ[i] += o.JJ[i]; wIJ[i] += o.IJ[i];
        }
      }
      if (lv) {
        const float* Ir = Ip + (size_t)rl * W;
        const float* Jr = Jp + (size_t)rl * W;
        float4 iL = ld4(Ir + xl), iC = ld4(Ir + X), iR = ld4(Ir + xr);
        float4 jL = ld4(Jr + xl), jC = ld4(Jr + X), jR = ld4(Jr + xr);
        if (!okL) { iL = make_float4(0,0,0,0); jL = make_float4(0,0,0,0); }
        if (!okR) { iR = make_float4(0,0,0,0); jR = make_float4(0,0,0,0); }
        RS o; rowsum(iL,iC,iR,jL,jC,jR,o);
        #pragma unroll
        for (int i = 0; i < CPT; ++i) {
          wI[i] -= o.I[i];  wJ[i] -= o.J[i];
          wII[i] -= o.II[i]; wJJ[i] -= o.JJ[i]; wIJ[i] -= o.IJ[i];
        }
      }
    }
    #pragma unroll
    for (int i = 0; i < CPT; ++i) {
      float cross = fmaf(-(wI[i] * wJ[i]), inv81, wIJ[i]);
      float Iv    = fmaf(-(wI[i] * wI[i]), inv81, wII[i]);
      float Jv    = fmaf(-(wJ[i] * wJ[i]), inv81, wJJ[i]);
      acc = fmaf(cross * cross,
                 __builtin_amdgcn_rcpf(fmaf(Iv, Jv, EPS)), acc);
    }
  }

  // ---- wave reduction -> one partial per wave ----
  #pragma unroll
  for (int off = 32; off > 0; off >>= 1)
    acc += __shfl_down(acc, off, 64);
  if (lane == 0) {
    const int wid = ((int)n * NBYT + gy) * NBX + gx;
    partial[wid] = acc;
  }
}

__global__ __launch_bounds__(256)
void ncc_reduce(const float* __restrict__ partial, float* __restrict__ out) {
  __shared__ float red[4];
  const int tid = threadIdx.x;
  const float4* p4 = reinterpret_cast<const float4*>(partial);
  float s = 0.f;
  #pragma unroll
  for (int i = tid; i < NWAVES / 4; i += 256) {
    float4 v = p4[i];
    s += (v.x + v.y) + (v.z + v.w);
  }
  #pragma unroll
  for (int off = 32; off > 0; off >>= 1)
    s += __shfl_down(s, off, 64);
  if ((tid & 63) == 0) red[tid >> 6] = s;
  __syncthreads();
  if (tid == 0)
    out[0] = (red[0] + red[1] + red[2] + red[3]) *
             (1.0f / (float)((size_t)NIMG * H * W));
}

extern "C" void kernel_launch(void* const* d_in, const int* in_sizes, int n_in,
                              void* d_out, int out_size, void* d_ws, size_t ws_size,
                              hipStream_t stream) {
  const float* I = (const float*)d_in[0];
  const float* J = (const float*)d_in[1];
  float* out     = (float*)d_out;
  float* partial = (float*)d_ws;            // 4096 * 4 B = 16 KiB

  // grid = (x, image, ytile): 32 blocks per ytile-slice -> each (gx,n) keeps
  // a constant XCD across gy (8-XCD round robin), so vertical halo rows of
  // consecutive tiles hit the same XCD's L2.
  dim3 grid(NBX, NIMG, NBYT);               // 4 x 8 x 128 = 4096 blocks
  hipLaunchKernelGGL(ncc_main, grid, dim3(64), 0, stream, I, J, partial);
  hipLaunchKernelGGL(ncc_reduce, dim3(1), dim3(256), 0, stream, partial, out);
}

// Round 11
// 117.065 us; speedup vs baseline: 1.0075x; 1.0075x over previous
//
#include <hip/hip_runtime.h>

#define H 1024
#define W 1024
#define NIMG 8
#define CPT 4                  // columns per thread
#define TH 8                   // output rows per wave-tile
#define NBX 4                  // 64 lanes * 4 cols * 4 = 1024 cols
#define NBYT (H / TH)          // 128 y-tiles
#define WPB 2                  // independent waves per block (no coupling)
#define NWAVES (NBX * NBYT * NIMG)   // 4096 waves in 2048 blocks
#define EPS 1e-5f

struct RS { float I[CPT], J[CPT], II[CPT], JJ[CPT], IJ[CPT]; };

__device__ __forceinline__ float4 ld4(const float* p) {
  return *reinterpret_cast<const float4*>(p);
}

// Horizontal 9-box rowsums for 4 output columns from 12 raw px.
__device__ __forceinline__ void rowsum(const float4& iL, const float4& iC,
                                       const float4& iR, const float4& jL,
                                       const float4& jC, const float4& jR,
                                       RS& o) {
  const float a[12] = {iL.x,iL.y,iL.z,iL.w, iC.x,iC.y,iC.z,iC.w,
                       iR.x,iR.y,iR.z,iR.w};
  const float b[12] = {jL.x,jL.y,jL.z,jL.w, jC.x,jC.y,jC.z,jC.w,
                       jR.x,jR.y,jR.z,jR.w};
  float sI=0.f, sJ=0.f, sII=0.f, sJJ=0.f, sIJ=0.f;
  #pragma unroll
  for (int k = 0; k < 9; ++k) {
    sI += a[k]; sJ += b[k];
    sII = fmaf(a[k], a[k], sII);
    sJJ = fmaf(b[k], b[k], sJJ);
    sIJ = fmaf(a[k], b[k], sIJ);
  }
  o.I[0]=sI; o.J[0]=sJ; o.II[0]=sII; o.JJ[0]=sJJ; o.IJ[0]=sIJ;
  #pragma unroll
  for (int i = 1; i < CPT; ++i) {
    float an=a[i+8], al=a[i-1], bn=b[i+8], bl=b[i-1];
    sI += an - al;  sJ += bn - bl;
    sII = fmaf(-al, al, fmaf(an, an, sII));
    sJJ = fmaf(-bl, bl, fmaf(bn, bn, sJJ));
    sIJ = fmaf(-al, bl, fmaf(an, bn, sIJ));
    o.I[i]=sI; o.J[i]=sJ; o.II[i]=sII; o.JJ[i]=sJJ; o.IJ[i]=sIJ;
  }
}

// 2 independent waves per block (no LDS, no barriers). KEY vs R10: a
// sched_barrier(0) pins all 12 loads of a steady iteration BEFORE any
// consumer, forcing one waitcnt cluster per iteration (R10's VGPR=44
// proved the compiler was serializing 2-3 memory round trips/iter).
__global__ __launch_bounds__(128, 4)
void ncc_main(const float* __restrict__ I, const float* __restrict__ J,
              float* __restrict__ partial) {
  const int lane = threadIdx.x & 63;
  const int wv   = threadIdx.x >> 6;      // 0/1 -> own y-tile
  const int gx = blockIdx.x;
  const int n  = blockIdx.y;              // image (XCD-constant per (gx,n))
  const int gy = blockIdx.z * WPB + wv;
  const int X  = gx * 256 + lane * CPT;
  const int y0 = gy * TH;
  const bool okL = (X >= 4);
  const bool okR = (X + 8 <= W);
  const int xl = okL ? X - 4 : X;         // clamped (loop-invariant)
  const int xr = okR ? X + 4 : X;
  const size_t img_off = (size_t)n * H * W;
  const float* Ip = I + img_off;
  const float* Jp = J + img_off;

  float wI[CPT], wJ[CPT], wII[CPT], wJJ[CPT], wIJ[CPT];
  #pragma unroll
  for (int i = 0; i < CPT; ++i) { wI[i]=wJ[i]=wII[i]=wJJ[i]=wIJ[i]=0.f; }
  float acc = 0.f;
  const float inv81 = 1.0f / 81.0f;

  // ---- warm-up: rows y0-4 .. y0+4 (9 rows) -> window for output y0 ----
  #pragma unroll 1
  for (int k = 0; k < 9; ++k) {
    const int r = y0 - 4 + k;
    if ((unsigned)r < (unsigned)H) {      // wave-uniform
      const float* Ir = Ip + (size_t)r * W;
      const float* Jr = Jp + (size_t)r * W;
      float4 iL = ld4(Ir + xl), iC = ld4(Ir + X), iR = ld4(Ir + xr);
      float4 jL = ld4(Jr + xl), jC = ld4(Jr + X), jR = ld4(Jr + xr);
      __builtin_amdgcn_sched_barrier(0);
      if (!okL) { iL = make_float4(0,0,0,0); jL = make_float4(0,0,0,0); }
      if (!okR) { iR = make_float4(0,0,0,0); jR = make_float4(0,0,0,0); }
      RS o; rowsum(iL,iC,iR,jL,jC,jR,o);
      #pragma unroll
      for (int i = 0; i < CPT; ++i) {
        wI[i] += o.I[i];  wJ[i] += o.J[i];
        wII[i] += o.II[i]; wJJ[i] += o.JJ[i]; wIJ[i] += o.IJ[i];
      }
    }
  }
  #pragma unroll
  for (int i = 0; i < CPT; ++i) {
    float cross = fmaf(-(wI[i] * wJ[i]), inv81, wIJ[i]);
    float Iv    = fmaf(-(wI[i] * wI[i]), inv81, wII[i]);
    float Jv    = fmaf(-(wJ[i] * wJ[i]), inv81, wJJ[i]);
    acc = fmaf(cross * cross,
               __builtin_amdgcn_rcpf(fmaf(Iv, Jv, EPS)), acc);
  }

  // ---- steady: enter y0+5+k, leave y0-4+k, emit y0+1+k ----
  #pragma unroll 1
  for (int k = 0; k < TH - 1; ++k) {
    const int re = y0 + 5 + k;
    const int rl = y0 - 4 + k;
    const bool ev = (unsigned)re < (unsigned)H;   // wave-uniform
    const bool lv = (unsigned)rl < (unsigned)H;   // wave-uniform
    if (ev & lv) {
      const float* IrE = Ip + (size_t)re * W;
      const float* JrE = Jp + (size_t)re * W;
      const float* IrL = Ip + (size_t)rl * W;
      const float* JrL = Jp + (size_t)rl * W;
      // ALL 12 loads, then a hard scheduling fence: nothing crosses.
      float4 eiL = ld4(IrE + xl), eiC = ld4(IrE + X), eiR = ld4(IrE + xr);
      float4 ejL = ld4(JrE + xl), ejC = ld4(JrE + X), ejR = ld4(JrE + xr);
      float4 liL = ld4(IrL + xl), liC = ld4(IrL + X), liR = ld4(IrL + xr);
      float4 ljL = ld4(JrL + xl), ljC = ld4(JrL + X), ljR = ld4(JrL + xr);
      __builtin_amdgcn_sched_barrier(0);
      if (!okL) {
        eiL = make_float4(0,0,0,0); ejL = make_float4(0,0,0,0);
        liL = make_float4(0,0,0,0); ljL = make_float4(0,0,0,0);
      }
      if (!okR) {
        eiR = make_float4(0,0,0,0); ejR = make_float4(0,0,0,0);
        liR = make_float4(0,0,0,0); ljR = make_float4(0,0,0,0);
      }
      RS oe, ol;
      rowsum(eiL,eiC,eiR,ejL,ejC,ejR,oe);
      rowsum(liL,liC,liR,ljL,ljC,ljR,ol);
      #pragma unroll
      for (int i = 0; i < CPT; ++i) {
        wI[i]  += oe.I[i]  - ol.I[i];
        wJ[i]  += oe.J[i]  - ol.J[i];
        wII[i] += oe.II[i] - ol.II[i];
        wJJ[i] += oe.JJ[i] - ol.JJ[i];
        wIJ[i] += oe.IJ[i] - ol.IJ[i];
      }
    } else {
      // rare y-edge path (first/last tile of each image)
      if (ev) {
        const float* Ir = Ip + (size_t)re * W;
        const float* Jr = Jp + (size_t)re * W;
        float4 iL = ld4(Ir + xl), iC = ld4(Ir + X), iR = ld4(Ir + xr);
        float4 jL = ld4(Jr + xl), jC = ld4(Jr + X), jR = ld4(Jr + xr);
        if (!okL) { iL = make_float4(0,0,0,0); jL = make_float4(0,0,0,0); }
        if (!okR) { iR = make_float4(0,0,0,0); jR = make_float4(0,0,0,0); }
        RS o; rowsum(iL,iC,iR,jL,jC,jR,o);
        #pragma unroll
        for (int i = 0; i < CPT; ++i) {
          wI[i] += o.I[i];  wJ[i] += o.J[i];
          wII[i] += o.II[i]; wJJ[i] += o.JJ[i]; wIJ[i] += o.IJ[i];
        }
      }
      if (lv) {
        const float* Ir = Ip + (size_t)rl * W;
        const float* Jr = Jp + (size_t)rl * W;
        float4 iL = ld4(Ir + xl), iC = ld4(Ir + X), iR = ld4(Ir + xr);
        float4 jL = ld4(Jr + xl), jC = ld4(Jr + X), jR = ld4(Jr + xr);
        if (!okL) { iL = make_float4(0,0,0,0); jL = make_float4(0,0,0,0); }
        if (!okR) { iR = make_float4(0,0,0,0); jR = make_float4(0,0,0,0); }
        RS o; rowsum(iL,iC,iR,jL,jC,jR,o);
        #pragma unroll
        for (int i = 0; i < CPT; ++i) {
          wI[i] -= o.I[i];  wJ[i] -= o.J[i];
          wII[i] -= o.II[i]; wJJ[i] -= o.JJ[i]; wIJ[i] -= o.IJ[i];
        }
      }
    }
    #pragma unroll
    for (int i = 0; i < CPT; ++i) {
      float cross = fmaf(-(wI[i] * wJ[i]), inv81, wIJ[i]);
      float Iv    = fmaf(-(wI[i] * wI[i]), inv81, wII[i]);
      float Jv    = fmaf(-(wJ[i] * wJ[i]), inv81, wJJ[i]);
      acc = fmaf(cross * cross,
                 __builtin_amdgcn_rcpf(fmaf(Iv, Jv, EPS)), acc);
    }
  }

  // ---- wave reduction -> one partial per wave ----
  #pragma unroll
  for (int off = 32; off > 0; off >>= 1)
    acc += __shfl_down(acc, off, 64);
  if (lane == 0) {
    const int wid = ((int)n * NBYT + gy) * NBX + gx;
    partial[wid] = acc;
  }
}

__global__ __launch_bounds__(256)
void ncc_reduce(const float* __restrict__ partial, float* __restrict__ out) {
  __shared__ float red[4];
  const int tid = threadIdx.x;
  const float4* p4 = reinterpret_cast<const float4*>(partial);
  float s = 0.f;
  #pragma unroll
  for (int i = tid; i < NWAVES / 4; i += 256) {
    float4 v = p4[i];
    s += (v.x + v.y) + (v.z + v.w);
  }
  #pragma unroll
  for (int off = 32; off > 0; off >>= 1)
    s += __shfl_down(s, off, 64);
  if ((tid & 63) == 0) red[tid >> 6] = s;
  __syncthreads();
  if (tid == 0)
    out[0] = (red[0] + red[1] + red[2] + red[3]) *
             (1.0f / (float)((size_t)NIMG * H * W));
}

extern "C" void kernel_launch(void* const* d_in, const int* in_sizes, int n_in,
                              void* d_out, int out_size, void* d_ws, size_t ws_size,
                              hipStream_t stream) {
  const float* I = (const float*)d_in[0];
  const float* J = (const float*)d_in[1];
  float* out     = (float*)d_out;
  float* partial = (float*)d_ws;            // 4096 * 4 B = 16 KiB

  // grid = (x, image, ytile-pair): 32 blocks per z-slice -> (gx,n) pins the
  // XCD across gy, so vertical halo rows stay in one XCD's L2.
  dim3 grid(NBX, NIMG, NBYT / WPB);         // 4 x 8 x 64 = 2048 blocks
  hipLaunchKernelGGL(ncc_main, grid, dim3(128), 0, stream, I, J, partial);
  hipLaunchKernelGGL(ncc_reduce, dim3(1), dim3(256), 0, stream, partial, out);
}